// Round 6
// baseline (208.828 us; speedup 1.0000x reference)
//
#include <hip/hip_runtime.h>

// ALiBi attention block, MI355X. B=2, T=2048, C=1024, NH=16, HD=64.
// fp32 in / fp32 out; bf16 MFMA compute.
// Pipeline: convert x | transpose weights | fused QKV GEMM (128x128,
// global_load_lds, V routed transposed) | flash attn (512 thr, 128-row
// q macro-tile, 2 j-groups x 4 waves x 32 q-rows, shared K/V staging,
// fixed-max softmax, additive combine) | out-proj GEMM (fp32 out).
// ws (u16): wqkvT[0,3M) woT[3M,4M) xc[4M,8M) qbuf[8M,12M) vtbuf[12M,16M).
// K staged bf16 in d_out (16 MB fp32 buf), overwritten by final GEMM.

typedef unsigned short u16;
typedef unsigned int u32;
typedef __attribute__((ext_vector_type(8))) short bf16x8;      // 8 bf16 = 4 VGPR
typedef __attribute__((ext_vector_type(4))) float f32x4;
typedef __attribute__((ext_vector_type(4))) unsigned short u16x4;

#define MFMA16x16(A, B, C_) __builtin_amdgcn_mfma_f32_16x16x32_bf16((A), (B), (C_), 0, 0, 0)

__device__ __forceinline__ u16 f2bf(float f) {
  u32 x = __builtin_bit_cast(u32, f);
  x += 0x7fff + ((x >> 16) & 1);   // RNE
  return (u16)(x >> 16);
}

// async global->LDS, 16B/lane; LDS dest = wave-uniform base + lane*16
__device__ __forceinline__ void gload_lds16(const u16* g, u16* l) {
  __builtin_amdgcn_global_load_lds(
      (const __attribute__((address_space(1))) void*)g,
      (__attribute__((address_space(3))) void*)l, 16, 0, 0);
}

constexpr int T = 2048, C = 1024, HD = 64;
constexpr int BT = 2 * T;  // 4096

// XOR-swizzled frag read: element (row, k) lives at chunk (k>>3)^(row&7).
__device__ __forceinline__ bf16x8 ldsfrag(const u16* lds, int row, int kchunk) {
  return *(const bf16x8*)(lds + row * 64 + (((kchunk) ^ (row & 7)) << 3));
}

// ---------------- convert x (fp32) -> bf16 ----------------
__global__ __launch_bounds__(256) void convert_x_kernel(
    const float* __restrict__ xin, u16* __restrict__ xc) {
  int i = (blockIdx.x * 256 + threadIdx.x) * 8;
  const float4 a = *(const float4*)(xin + i);
  const float4 b = *(const float4*)(xin + i + 4);
  uint4 o;
  o.x = (u32)f2bf(a.x) | ((u32)f2bf(a.y) << 16);
  o.y = (u32)f2bf(a.z) | ((u32)f2bf(a.w) << 16);
  o.z = (u32)f2bf(b.x) | ((u32)f2bf(b.y) << 16);
  o.w = (u32)f2bf(b.z) | ((u32)f2bf(b.w) << 16);
  *(uint4*)(xc + i) = o;
}

// ---------------- transpose 4 fp32 weights -> bf16 ----------------
__global__ __launch_bounds__(256) void transpose4_kernel(
    const float* __restrict__ w0, const float* __restrict__ w1,
    const float* __restrict__ w2, const float* __restrict__ w3,
    u16* __restrict__ wqkvT, u16* __restrict__ woT) {
  __shared__ u16 tile[32][33];
  const int z = blockIdx.z;
  const float* in = (z == 0) ? w0 : (z == 1) ? w1 : (z == 2) ? w2 : w3;
  u16* out = (z < 3) ? (wqkvT + (size_t)z * (1u << 20)) : woT;
  int tx = threadIdx.x, ty = threadIdx.y;
  int x = blockIdx.x * 32 + tx;
#pragma unroll
  for (int i = 0; i < 4; i++) {
    int y = blockIdx.y * 32 + ty + i * 8;
    tile[ty + i * 8][tx] = f2bf(in[y * 1024 + x]);
  }
  __syncthreads();
  int xo = blockIdx.y * 32 + tx;
#pragma unroll
  for (int i = 0; i < 4; i++) {
    int yo = blockIdx.x * 32 + ty + i * 8;
    out[yo * 1024 + xo] = tile[tx][ty + i * 8];
  }
}

// ---------------- fused QKV GEMM: 128x128 tile, K=1024 ----------------
__global__ __launch_bounds__(256) void gemm_qkv_kernel(
    const u16* __restrict__ A, const u16* __restrict__ Bt,
    const float* __restrict__ b0, const float* __restrict__ b1,
    const float* __restrict__ b2,
    u16* __restrict__ qout, u16* __restrict__ kout, u16* __restrict__ vtout) {
  constexpr int K = 1024;
  __shared__ __align__(16) u16 As[128 * 64];
  __shared__ __align__(16) u16 Bs[128 * 64];

  const int tid = threadIdx.x;
  const int w = tid >> 6, lane = tid & 63;
  const int l15 = lane & 15, quad = lane >> 4;
  const int m0 = blockIdx.y * 128, n0 = blockIdx.x * 128;
  const int wm = (w >> 1) * 64, wn = (w & 1) * 64;
  const int gsub = (lane & 7) ^ ((lane >> 3) & 7);
  const int rsub = lane >> 3;

  f32x4 acc[4][4] = {};
  const u16* Ag = A + (size_t)m0 * K;
  const u16* Bg = Bt + (size_t)n0 * K;

  for (int k0 = 0; k0 < K; k0 += 64) {
    __syncthreads();
#pragma unroll
    for (int t = 0; t < 4; t++) {
      int rbase = w * 32 + t * 8;
      gload_lds16(Ag + (size_t)(rbase + rsub) * K + k0 + gsub * 8, As + rbase * 64);
      gload_lds16(Bg + (size_t)(rbase + rsub) * K + k0 + gsub * 8, Bs + rbase * 64);
    }
    __syncthreads();
#pragma unroll
    for (int ks = 0; ks < 2; ks++) {
      bf16x8 af[4], bf[4];
#pragma unroll
      for (int mi = 0; mi < 4; mi++)
        af[mi] = ldsfrag(As, wm + mi * 16 + l15, (ks << 2) | quad);
#pragma unroll
      for (int ni = 0; ni < 4; ni++)
        bf[ni] = ldsfrag(Bs, wn + ni * 16 + l15, (ks << 2) | quad);
#pragma unroll
      for (int mi = 0; mi < 4; mi++)
#pragma unroll
        for (int ni = 0; ni < 4; ni++)
          acc[mi][ni] = MFMA16x16(af[mi], bf[ni], acc[mi][ni]);
    }
  }

  const int sel = n0 >> 10;       // 0=Q,1=K,2=V
  const int nloc = n0 & 1023;
  if (sel < 2) {
    u16* D = (sel == 0) ? qout : kout;
    const float* bias = (sel == 0) ? b0 : b1;
#pragma unroll
    for (int mi = 0; mi < 4; mi++)
#pragma unroll
      for (int ni = 0; ni < 4; ni++) {
        int rb = m0 + wm + mi * 16 + quad * 4;
        int col = nloc + wn + ni * 16 + l15;
        float bb = bias[col];
#pragma unroll
        for (int r = 0; r < 4; r++)
          D[(size_t)(rb + r) * 1024 + col] = f2bf(acc[mi][ni][r] + bb);
      }
  } else {
#pragma unroll
    for (int mi = 0; mi < 4; mi++)
#pragma unroll
      for (int ni = 0; ni < 4; ni++) {
        int rb = m0 + wm + mi * 16 + quad * 4;
        int c = nloc + wn + ni * 16 + l15;
        float bb = b2[c];
        u16x4 pk;
#pragma unroll
        for (int r = 0; r < 4; r++) pk[r] = f2bf(acc[mi][ni][r] + bb);
        *(u16x4*)(vtout + (size_t)c * 4096 + rb) = pk;
      }
  }
}

// ---------------- out-proj GEMM: 128x64 tile, fp32 out ----------------
__global__ __launch_bounds__(256) void gemm_out_kernel(
    const u16* __restrict__ A, const u16* __restrict__ Bt,
    const float* __restrict__ bias, float* __restrict__ fout) {
  constexpr int K = 1024;
  __shared__ __align__(16) u16 As[128 * 64];
  __shared__ __align__(16) u16 Bs[64 * 64];

  const int tid = threadIdx.x;
  const int w = tid >> 6, lane = tid & 63;
  const int l15 = lane & 15, quad = lane >> 4;
  const int m0 = blockIdx.y * 128, n0 = blockIdx.x * 64;
  const int wm = (w >> 1) * 64, wn = (w & 1) * 32;
  const int gsub = (lane & 7) ^ ((lane >> 3) & 7);
  const int rsub = lane >> 3;

  f32x4 acc[4][2] = {};
  const u16* Ag = A + (size_t)m0 * K;
  const u16* Bg = Bt + (size_t)n0 * K;

  for (int k0 = 0; k0 < K; k0 += 64) {
    __syncthreads();
#pragma unroll
    for (int t = 0; t < 4; t++) {
      int rbase = w * 32 + t * 8;
      gload_lds16(Ag + (size_t)(rbase + rsub) * K + k0 + gsub * 8, As + rbase * 64);
    }
#pragma unroll
    for (int t = 0; t < 2; t++) {
      int rbase = w * 16 + t * 8;
      gload_lds16(Bg + (size_t)(rbase + rsub) * K + k0 + gsub * 8, Bs + rbase * 64);
    }
    __syncthreads();
#pragma unroll
    for (int ks = 0; ks < 2; ks++) {
      bf16x8 af[4], bf[2];
#pragma unroll
      for (int mi = 0; mi < 4; mi++)
        af[mi] = ldsfrag(As, wm + mi * 16 + l15, (ks << 2) | quad);
#pragma unroll
      for (int ni = 0; ni < 2; ni++)
        bf[ni] = ldsfrag(Bs, wn + ni * 16 + l15, (ks << 2) | quad);
#pragma unroll
      for (int mi = 0; mi < 4; mi++)
#pragma unroll
        for (int ni = 0; ni < 2; ni++)
          acc[mi][ni] = MFMA16x16(af[mi], bf[ni], acc[mi][ni]);
    }
  }

#pragma unroll
  for (int mi = 0; mi < 4; mi++)
#pragma unroll
    for (int ni = 0; ni < 2; ni++) {
      int rb = m0 + wm + mi * 16 + quad * 4;
      int col = n0 + wn + ni * 16 + l15;
      float bb = bias[col];
#pragma unroll
      for (int r = 0; r < 4; r++)
        fout[(size_t)(rb + r) * 1024 + col] = acc[mi][ni][r] + bb;
    }
}

// ---------------- flash attention: 128-row q macro-tile ----------------
// 512 threads = 8 waves = 2 j-groups (g) x 4 waves (wq); each wave owns 32
// q-rows (2 sub-tiles of 16) sharing all K/V fragment reads and staging.
// Group g handles j-tile jtv = 2*it + g; iters = qt128+1 (no dead tiles).
// Block p: qt128 = 15-p then p -> 17 iters total, balanced. Fixed-max
// softmax (scores bounded; masked elems may hit +inf pre-mask, then 0).
// LDS 48 KB: Qs[128x64] (aliased as per-wave P bufs + Lsc) | KVs 4x[64x64]
// (aliased as Osc f32 scratch for the group combine).
__global__ __launch_bounds__(512, 2) void attn_kernel(
    const u16* __restrict__ qbuf, const u16* __restrict__ kbuf,
    const u16* __restrict__ vtbuf, u16* __restrict__ ybuf) {
  __shared__ __align__(16) u16 SMEM[24576];   // 48 KB

  const int tid = threadIdx.x;
  const int w = tid >> 6, lane = tid & 63;
  const int wq = w & 3, g = w >> 2;
  const int l15 = lane & 15, quad = lane >> 4;
  const int bh = blockIdx.y, b = bh >> 4, h = bh & 15;
  const float slope = exp2f(-0.5f * (float)(h + 1));
  const float slope128 = slope * 128.f;
  const float s16 = slope * 16.f;
  const int gsub = (lane & 7) ^ ((lane >> 3) & 7);
  const int rsub = lane >> 3;

  u16* Qs = SMEM;                 // 128x64, later per-wave P + Lsc
  u16* KVs = SMEM + 8192;         // 4 x 64x64, later Osc
  u16* Pw = SMEM + w * 1024;      // per-wave 16x64 P buffer (aliases Qs)

  const u16* kbase0 = kbuf + (size_t)b * T * C + h * HD;
  const u16* vtbase0 = vtbuf + (size_t)h * HD * BT + (size_t)b * T;

  const int st = w >> 1;          // staging tile: 0=K|jt0 1=K|jt1 2=V|jt0 3=V|jt1
  const int skind = st >> 1;
  const int sjt = st & 1;
  const int srb = (w & 1) * 32;

#pragma unroll 1
  for (int half = 0; half < 2; half++) {
    const int qt = half == 0 ? (15 - (int)blockIdx.x) : (int)blockIdx.x;  // qt128
    const int qrow_g = b * T + qt * 128;

    __syncthreads();  // prior epilogue reads of SMEM done
    const u16* qb = qbuf + (size_t)qrow_g * C + h * HD;
#pragma unroll
    for (int t = 0; t < 2; t++)
      gload_lds16(qb + (size_t)(w * 16 + t * 8 + rsub) * C + gsub * 8,
                  Qs + (w * 16 + t * 8) * 64);
    __syncthreads();
    bf16x8 aq[2][2];
#pragma unroll
    for (int sb = 0; sb < 2; sb++) {
      aq[sb][0] = ldsfrag(Qs, wq * 32 + sb * 16 + l15, quad);
      aq[sb][1] = ldsfrag(Qs, wq * 32 + sb * 16 + l15, 4 + quad);
    }

    f32x4 o[2][4] = {};
    float lsum[2][4] = {};
    const int ig00 = qt * 128 + wq * 32;   // wave's min seq row (sub 0)
    float br[4][4];                        // slope*(j - i), sub 0, jtv = g
#pragma unroll
    for (int ni = 0; ni < 4; ni++)
#pragma unroll
      for (int r = 0; r < 4; r++)
        br[ni][r] = slope * (float)(g * 64 + ni * 16 + l15 - ig00 - quad * 4 - r);

    const int iters = qt + 1;
#pragma unroll 1
    for (int it = 0; it < iters; it++) {
      __syncthreads();  // all waves done with previous K/V frag reads
      {
        int jt = 2 * it + sjt;
        const u16* base = skind ? (vtbase0 + jt * 64)
                                : (kbase0 + (size_t)jt * 64 * C);
        const int stride = skind ? BT : C;
        u16* dst = KVs + st * 4096 + srb * 64;
#pragma unroll
        for (int c2 = 0; c2 < 4; c2++)
          gload_lds16(base + (size_t)(srb + c2 * 8 + rsub) * stride + gsub * 8,
                      dst + c2 * 8 * 64);
      }
      __syncthreads();  // staging visible

      const int jtv = 2 * it + g;
      const u16* Kw = KVs + g * 4096;
      const u16* Vw = KVs + (2 + g) * 4096;

      // S for both 16-row sub-tiles, sharing every K fragment read
      f32x4 s[2][4];
#pragma unroll
      for (int ni = 0; ni < 4; ni++) {
        bf16x8 kf0 = ldsfrag(Kw, ni * 16 + l15, quad);
        bf16x8 kf1 = ldsfrag(Kw, ni * 16 + l15, 4 + quad);
#pragma unroll
        for (int sb = 0; sb < 2; sb++) {
          f32x4 z = {0.f, 0.f, 0.f, 0.f};
          z = MFMA16x16(aq[sb][0], kf0, z);
          z = MFMA16x16(aq[sb][1], kf1, z);
          s[sb][ni] = z;
        }
      }

#pragma unroll
      for (int sb = 0; sb < 2; sb++) {
        const float boff = sb ? s16 : 0.f;
        const int igs = ig00 + sb * 16 + quad * 4;
        const bool edge = (jtv * 64 + 63) > (ig00 + sb * 16);
#pragma unroll
        for (int ni = 0; ni < 4; ni++)
#pragma unroll
          for (int r = 0; r < 4; r++) {
            float p = __expf(fmaf(s[sb][ni][r], 0.125f, br[ni][r] - boff));
            if (edge && (jtv * 64 + ni * 16 + l15) > (igs + r)) p = 0.f;
            lsum[sb][r] += p;
            int prow = quad * 4 + r, pcol = ni * 16 + l15;
            Pw[prow * 64 + (((pcol >> 3) ^ (prow & 7)) << 3) + (pcol & 7)] = f2bf(p);
          }
        // per-wave P buffer; same-wave DS ops are in-order -> no barrier
        bf16x8 pa0 = ldsfrag(Pw, l15, quad);
        bf16x8 pa1 = ldsfrag(Pw, l15, 4 + quad);
#pragma unroll
        for (int ni = 0; ni < 4; ni++) {
          bf16x8 vf0 = ldsfrag(Vw, ni * 16 + l15, quad);
          bf16x8 vf1 = ldsfrag(Vw, ni * 16 + l15, 4 + quad);
          o[sb][ni] = MFMA16x16(pa0, vf0, o[sb][ni]);
          o[sb][ni] = MFMA16x16(pa1, vf1, o[sb][ni]);
        }
      }
#pragma unroll
      for (int ni = 0; ni < 4; ni++)
#pragma unroll
        for (int r = 0; r < 4; r++) br[ni][r] += slope128;
    }

    // combine the two j-groups (pure sums), normalize, write y
    __syncthreads();
    float* Osc = (float*)(SMEM + 8192);  // 128x64 f32 = 32 KB
    float* Lsc = (float*)SMEM;           // 128x16 f32 = 8 KB
    if (g == 1) {
#pragma unroll
      for (int sb = 0; sb < 2; sb++) {
#pragma unroll
        for (int ni = 0; ni < 4; ni++)
#pragma unroll
          for (int r = 0; r < 4; r++)
            Osc[(wq * 32 + sb * 16 + quad * 4 + r) * 64 + ni * 16 + l15] = o[sb][ni][r];
#pragma unroll
        for (int r = 0; r < 4; r++)
          Lsc[(wq * 32 + sb * 16 + quad * 4 + r) * 16 + l15] = lsum[sb][r];
      }
    }
    __syncthreads();
    if (g == 0) {
#pragma unroll
      for (int sb = 0; sb < 2; sb++)
#pragma unroll
        for (int r = 0; r < 4; r++) {
          int lrow = wq * 32 + sb * 16 + quad * 4 + r;
          float l = lsum[sb][r] + Lsc[lrow * 16 + l15];
          l += __shfl_xor(l, 1);
          l += __shfl_xor(l, 2);
          l += __shfl_xor(l, 4);
          l += __shfl_xor(l, 8);
          float inv = 1.f / l;
          u16* yrow = ybuf + (size_t)(qrow_g + lrow) * C + h * HD;
#pragma unroll
          for (int ni = 0; ni < 4; ni++)
            yrow[ni * 16 + l15] =
                f2bf((o[sb][ni][r] + Osc[lrow * 64 + ni * 16 + l15]) * inv);
        }
    }
  }
}

extern "C" void kernel_launch(void* const* d_in, const int* in_sizes, int n_in,
                              void* d_out, int out_size, void* d_ws, size_t ws_size,
                              hipStream_t stream) {
  (void)in_sizes; (void)n_in; (void)out_size; (void)ws_size;
  const float* x  = (const float*)d_in[0];
  const float* Wq = (const float*)d_in[1];
  const float* bq = (const float*)d_in[2];
  const float* Wk = (const float*)d_in[3];
  const float* bk = (const float*)d_in[4];
  const float* Wv = (const float*)d_in[5];
  const float* bv = (const float*)d_in[6];
  const float* Wo = (const float*)d_in[7];
  const float* bo = (const float*)d_in[8];

  u16* ws = (u16*)d_ws;
  constexpr size_t M1 = 1u << 20;
  u16* wqkvT = ws;               // [3072,1024] = [WqT;WkT;WvT]
  u16* woT   = ws + 3 * M1;      // [1024,1024]
  u16* xc    = ws + 4 * M1;      // [4096,1024] bf16 x
  u16* qbuf  = ws + 8 * M1;      // [4096,1024] bf16 Q (later aliased as y)
  u16* vtbuf = ws + 12 * M1;     // [1024,4096] bf16 V^T
  u16* kbuf  = (u16*)d_out;      // bf16 K staged in d_out (16 MB fp32 buffer)
  u16* ybuf  = qbuf;             // safe alias: block overwrites only its own Q rows

  convert_x_kernel<<<2048, 256, 0, stream>>>(x, xc);
  transpose4_kernel<<<dim3(32, 32, 4), dim3(32, 8), 0, stream>>>(Wq, Wk, Wv, Wo, wqkvT, woT);
  gemm_qkv_kernel<<<dim3(24, 32), 256, 0, stream>>>(
      xc, wqkvT, bq, bk, bv, qbuf, kbuf, vtbuf);
  attn_kernel<<<dim3(8, 32), 512, 0, stream>>>(qbuf, kbuf, vtbuf, ybuf);
  gemm_out_kernel<<<dim3(16, 32), 256, 0, stream>>>(ybuf, woT, bo, (float*)d_out);
}